// Round 3
// baseline (367.969 us; speedup 1.0000x reference)
//
#include <hip/hip_runtime.h>
#include <hip/hip_bf16.h>
#include <math.h>

// ---------------- sizes ----------------
#define BATCH 128
#define SEQ   2048
#define FIN   128
#define DD    16
#define NLAYERS 6

// ws layout (floats)
#define BUFA_F  (BATCH*SEQ*DD)            // 4,194,304
#define BUFB_F  (BATCH*(SEQ/2)*DD)        // 2,097,152
#define U1_OFF  (BUFA_F + BUFB_F)
#define U2_OFF  (U1_OFF + NLAYERS*4096)
#define WT_OFF  (U2_OFF + NLAYERS*4096)
#define ENT_OFF (WT_OFF + NLAYERS*4096)

// ---------------- prep: u1 = mean_l u, u2 = mean_k u, wt = w transposed ----------------
__global__ __launch_bounds__(256) void k_prep(const float* __restrict__ u,
                                              const float* __restrict__ w,
                                              float* __restrict__ u1,
                                              float* __restrict__ u2,
                                              float* __restrict__ wt) {
    int l  = blockIdx.x;        // 0..5
    int ij = threadIdx.x;       // 0..255  (= i*16+j)
    const float* ub = u + (size_t)l*65536 + (size_t)ij*256;   // [k][l2]
    float a1[16], a2[16];
#pragma unroll
    for (int k = 0; k < 16; ++k) { a1[k] = 0.0f; a2[k] = 0.0f; }
#pragma unroll
    for (int k = 0; k < 16; ++k) {
#pragma unroll
        for (int z = 0; z < 16; ++z) {
            float v = ub[k*16 + z];
            a1[k] += v;
            a2[z] += v;
        }
    }
    float* u1p = u1 + (size_t)l*4096 + ij*16;
    float* u2p = u2 + (size_t)l*4096 + ij*16;
#pragma unroll
    for (int k = 0; k < 16; ++k) { u1p[k] = a1[k]*(1.0f/16.0f); u2p[k] = a2[k]*(1.0f/16.0f); }

    const float* wb = w + (size_t)l*4096;      // [a][i][j]
    float* wtp = wt + (size_t)l*4096 + ij*16;  // [i][j][a]
#pragma unroll
    for (int a = 0; a < 16; ++a) wtp[a] = wb[a*256 + ij];
}

// ---------------- embedding + normalize: 1 thread = 1 row, W via scalar loads ----------------
__global__ __launch_bounds__(256) void k_embed(const float* __restrict__ seq,
                                               const float* __restrict__ W,
                                               const float* __restrict__ bias,
                                               float* __restrict__ out) {
    int t = threadIdx.x;
    size_t row = (size_t)blockIdx.x*256 + t;
    const float4* rp = (const float4*)seq + row*32;
    float acc[16];
#pragma unroll
    for (int d = 0; d < 16; ++d) acc[d] = bias[d];

#pragma unroll 8
    for (int kk = 0; kk < 32; ++kk) {
        float4 rv = rp[kk];
        const float* wr = W + kk*64;      // rows 4kk..4kk+3, wave-uniform -> s_load
#pragma unroll
        for (int d = 0; d < 16; ++d) acc[d] = fmaf(rv.x, wr[d],      acc[d]);
#pragma unroll
        for (int d = 0; d < 16; ++d) acc[d] = fmaf(rv.y, wr[16 + d], acc[d]);
#pragma unroll
        for (int d = 0; d < 16; ++d) acc[d] = fmaf(rv.z, wr[32 + d], acc[d]);
#pragma unroll
        for (int d = 0; d < 16; ++d) acc[d] = fmaf(rv.w, wr[48 + d], acc[d]);
    }
    float p = 0.0f;
#pragma unroll
    for (int d = 0; d < 16; ++d) p = fmaf(acc[d], acc[d], p);
    float inv = 1.0f / fmaxf(sqrtf(p), 1e-12f);
    float4* op = (float4*)(out + row*16);
    op[0] = make_float4(acc[0]*inv,  acc[1]*inv,  acc[2]*inv,  acc[3]*inv);
    op[1] = make_float4(acc[4]*inv,  acc[5]*inv,  acc[6]*inv,  acc[7]*inv);
    op[2] = make_float4(acc[8]*inv,  acc[9]*inv,  acc[10]*inv, acc[11]*inv);
    op[3] = make_float4(acc[12]*inv, acc[13]*inv, acc[14]*inv, acc[15]*inv);
}

// ---------------- one MERA layer: wave = k-slice, coeffs via scalar loads ----------------
// Block: 256 threads = 4 waves; wave kg handles outputs k in [4kg,4kg+4) for 64 pairs.
// spl[64][36]: pair's 32 site floats. o1l/o2l[64][20]: intermediates.
__global__ __launch_bounds__(256) void k_layer(const float* __restrict__ in,
                                               float* __restrict__ outp,
                                               const float* __restrict__ u1g,
                                               const float* __restrict__ u2g,
                                               const float* __restrict__ wtg) {
    __shared__ float spl[64*36];
    __shared__ float o1l[64*20];
    __shared__ float o2l[64*20];
    int t  = threadIdx.x;
    int wl = t & 63;                                  // lane = pair
    int kg = __builtin_amdgcn_readfirstlane(t >> 6);  // wave-uniform k-slice 0..3

    // stage 64 pairs (512 float4) into LDS
    {
        const float4* ing = (const float4*)in + (size_t)blockIdx.x*512;
        float4 v0 = ing[t];
        float4 v1 = ing[t + 256];
        int p0 = t >> 3,         f0 = t & 7;
        int p1 = (t + 256) >> 3, f1 = (t + 256) & 7;
        *(float4*)&spl[p0*36 + f0*4] = v0;
        *(float4*)&spl[p1*36 + f1*4] = v1;
    }
    __syncthreads();

    // s1 (second site) into registers
    float s1[16];
#pragma unroll
    for (int g = 0; g < 4; ++g) {
        float4 v = *(const float4*)&spl[wl*36 + 16 + g*4];
        s1[g*4+0] = v.x; s1[g*4+1] = v.y; s1[g*4+2] = v.z; s1[g*4+3] = v.w;
    }

    const float* U1b = u1g + kg*4;
    const float* U2b = u2g + kg*4;
    float o1a[4] = {0,0,0,0}, o2a[4] = {0,0,0,0};
#pragma unroll 4
    for (int i = 0; i < 16; ++i) {
        float s0i = spl[wl*36 + i];
        const float* U1i = U1b + i*256;
        const float* U2i = U2b + i*256;
#pragma unroll
        for (int j = 0; j < 16; ++j) {
            float pij = s0i * s1[j];
            o1a[0] = fmaf(pij, U1i[j*16+0], o1a[0]);
            o1a[1] = fmaf(pij, U1i[j*16+1], o1a[1]);
            o1a[2] = fmaf(pij, U1i[j*16+2], o1a[2]);
            o1a[3] = fmaf(pij, U1i[j*16+3], o1a[3]);
            o2a[0] = fmaf(pij, U2i[j*16+0], o2a[0]);
            o2a[1] = fmaf(pij, U2i[j*16+1], o2a[1]);
            o2a[2] = fmaf(pij, U2i[j*16+2], o2a[2]);
            o2a[3] = fmaf(pij, U2i[j*16+3], o2a[3]);
        }
    }
    *(float4*)&o1l[wl*20 + kg*4] = make_float4(o1a[0], o1a[1], o1a[2], o1a[3]);
    *(float4*)&o2l[wl*20 + kg*4] = make_float4(o2a[0], o2a[1], o2a[2], o2a[3]);
    __syncthreads();

    float o2f[16];
#pragma unroll
    for (int g = 0; g < 4; ++g) {
        float4 v = *(const float4*)&o2l[wl*20 + g*4];
        o2f[g*4+0] = v.x; o2f[g*4+1] = v.y; o2f[g*4+2] = v.z; o2f[g*4+3] = v.w;
    }

    const float* WTb = wtg + kg*4;
    float acc[4] = {0,0,0,0};
#pragma unroll 4
    for (int i = 0; i < 16; ++i) {
        float o1i = o1l[wl*20 + i];
        const float* Wi = WTb + i*256;
#pragma unroll
        for (int j = 0; j < 16; ++j) {
            float q = o1i * o2f[j];
            acc[0] = fmaf(q, Wi[j*16+0], acc[0]);
            acc[1] = fmaf(q, Wi[j*16+1], acc[1]);
            acc[2] = fmaf(q, Wi[j*16+2], acc[2]);
            acc[3] = fmaf(q, Wi[j*16+3], acc[3]);
        }
    }
    size_t gp = (size_t)blockIdx.x*64 + wl;
    *(float4*)(outp + gp*16 + kg*4) = make_float4(acc[0], acc[1], acc[2], acc[3]);
}

// ---------------- phi_q part 1: per-matrix Jacobi, 384 independent blocks ----------------
__device__ __forceinline__ void rot_cs(float al, float be, float ga, float& c, float& s) {
    float ze = (be - al) / (2.0f * ga);
    float tt = copysignf(1.0f, ze) / (fabsf(ze) + sqrtf(1.0f + ze*ze));
    c = 1.0f / sqrtf(1.0f + tt*tt);
    s = c * tt;
}

__global__ __launch_bounds__(64) void k_phi(const float* __restrict__ sites,
                                            float* __restrict__ ent) {
    __shared__ float S[512];
    __shared__ float C[256];
    __shared__ float sv[16];
    int bid = blockIdx.x;
    int role = bid >> 7;          // 0: 16x16 interface, 1: left 8x8, 2: right 8x8
    int b = bid & 127;
    int t = threadIdx.x;
    const float* sp = sites + (size_t)b*512;

    if (role == 0) {
        for (int x = t; x < 512; x += 64) S[x] = sp[x];
        __syncthreads();
        for (int e = t; e < 256; e += 64) {
            int i = e & 15, j = e >> 4;
            float a = 0.0f;
            for (int k = 0; k < 16; ++k) a = fmaf(S[i*16+k], S[(16+j)*16+k], a);
            C[j*16 + i] = a;
        }
        __syncthreads();
        // 16x16 one-sided Jacobi: 8 pairs x 8 lanes (2 rows/lane)
        for (int sw = 0; sw < 12; ++sw) {
            for (int r = 0; r < 15; ++r) {
                int pr = t >> 3, sub = t & 7;
                int p, q;
                if (pr == 0) { p = 15; q = r; }
                else { p = (r + pr) % 15; q = (r + 15 - pr) % 15; }
                float u0 = C[p*16 + 2*sub],   u1v = C[p*16 + 2*sub + 1];
                float v0 = C[q*16 + 2*sub],   v1v = C[q*16 + 2*sub + 1];
                float al = u0*u0 + u1v*u1v;
                float be = v0*v0 + v1v*v1v;
                float ga = u0*v0 + u1v*v1v;
                al += __shfl_xor(al,1); al += __shfl_xor(al,2); al += __shfl_xor(al,4);
                be += __shfl_xor(be,1); be += __shfl_xor(be,2); be += __shfl_xor(be,4);
                ga += __shfl_xor(ga,1); ga += __shfl_xor(ga,2); ga += __shfl_xor(ga,4);
                if (ga != 0.0f) {
                    float c, s; rot_cs(al, be, ga, c, s);
                    C[p*16 + 2*sub]     = fmaf(c, u0, -s*v0);
                    C[p*16 + 2*sub + 1] = fmaf(c, u1v, -s*v1v);
                    C[q*16 + 2*sub]     = fmaf(s, u0,  c*v0);
                    C[q*16 + 2*sub + 1] = fmaf(s, u1v, c*v1v);
                }
                __syncthreads();
            }
        }
        if (t < 16) {
            float s2 = 0.0f;
            for (int rr = 0; rr < 16; ++rr) { float v = C[t*16+rr]; s2 = fmaf(v, v, s2); }
            sv[t] = sqrtf(s2);
        }
        __syncthreads();
        if (t == 0) {
            float sum = 0.0f;
            for (int i2 = 0; i2 < 16; ++i2) sum += sv[i2];
            float den = sum + 1e-8f;
            float e2 = 0.0f;
            for (int i2 = 0; i2 < 16; ++i2) {
                float sn = sv[i2] / den;
                e2 -= sn * logf(sn + 1e-8f);
            }
            ent[b] = e2;
        }
    } else {
        int ro = (role == 1) ? 0 : 256;     // rows 0..15 or 16..31
        for (int x = t; x < 256; x += 64) S[x] = sp[ro + x];
        __syncthreads();
        if (t < 64) {
            int i = t & 7, j = t >> 3;
            float a = 0.0f;
            for (int k = 0; k < 16; ++k) a = fmaf(S[i*16+k], S[(8+j)*16+k], a);
            C[j*8 + i] = a;
        }
        __syncthreads();
        // 8x8: 4 pairs x 8 lanes on lanes 0..31
        for (int sw = 0; sw < 12; ++sw) {
            for (int r = 0; r < 7; ++r) {
                if (t < 32) {
                    int pr = t >> 3, sub = t & 7;
                    int p, q;
                    if (pr == 0) { p = 7; q = r; }
                    else { p = (r + pr) % 7; q = (r + 7 - pr) % 7; }
                    float uu = C[p*8 + sub], vv = C[q*8 + sub];
                    float al = uu*uu, be = vv*vv, ga = uu*vv;
                    al += __shfl_xor(al,1); al += __shfl_xor(al,2); al += __shfl_xor(al,4);
                    be += __shfl_xor(be,1); be += __shfl_xor(be,2); be += __shfl_xor(be,4);
                    ga += __shfl_xor(ga,1); ga += __shfl_xor(ga,2); ga += __shfl_xor(ga,4);
                    if (ga != 0.0f) {
                        float c, s; rot_cs(al, be, ga, c, s);
                        C[p*8 + sub] = fmaf(c, uu, -s*vv);
                        C[q*8 + sub] = fmaf(s, uu,  c*vv);
                    }
                }
                __syncthreads();
            }
        }
        if (t < 8) {
            float s2 = 0.0f;
            for (int rr = 0; rr < 8; ++rr) { float v = C[t*8+rr]; s2 = fmaf(v, v, s2); }
            sv[t] = sqrtf(s2);
        }
        __syncthreads();
        if (t == 0) {
            float sum = 0.0f;
            for (int i2 = 0; i2 < 8; ++i2) sum += sv[i2];
            float den = sum + 1e-8f;
            float e2 = 0.0f;
            for (int i2 = 0; i2 < 8; ++i2) {
                float sn = sv[i2] / den;
                e2 -= sn * logf(sn + 1e-8f);
            }
            ent[role*128 + b] = e2;
        }
    }
}

// ---------------- phi_q part 2: combine entropies ----------------
__global__ __launch_bounds__(128) void k_phi2(const float* __restrict__ ent,
                                              float* __restrict__ phi) {
    int b = threadIdx.x;
    phi[b] = fmaxf(ent[b] - (ent[128 + b] + ent[256 + b]), 0.0f);
}

// ---------------- launcher ----------------
extern "C" void kernel_launch(void* const* d_in, const int* in_sizes, int n_in,
                              void* d_out, int out_size, void* d_ws, size_t ws_size,
                              hipStream_t stream) {
    const float* seq  = (const float*)d_in[0];
    const float* W    = (const float*)d_in[1];
    const float* bias = (const float*)d_in[2];
    const float* u    = (const float*)d_in[3];
    const float* w    = (const float*)d_in[4];
    float* out = (float*)d_out;
    float* ws  = (float*)d_ws;

    float* bufA = ws;
    float* bufB = ws + BUFA_F;
    float* u1   = ws + U1_OFF;
    float* u2   = ws + U2_OFF;
    float* wt   = ws + WT_OFF;
    float* entb = ws + ENT_OFF;

    k_prep <<<NLAYERS, 256, 0, stream>>>(u, w, u1, u2, wt);
    k_embed<<<(BATCH*SEQ)/256, 256, 0, stream>>>(seq, W, bias, bufA);

    const float* lin[6]  = { bufA, bufB, bufA, bufB, bufA, bufB };
    float*       lout[6] = { bufB, bufA, bufB, bufA, bufB, out  };
    int npairs = BATCH * (SEQ/2);
    for (int l = 0; l < NLAYERS; ++l) {
        k_layer<<<npairs/64, 256, 0, stream>>>(lin[l], lout[l],
                                               u1 + l*4096, u2 + l*4096, wt + l*4096);
        npairs >>= 1;
    }
    k_phi <<<3*BATCH, 64, 0, stream>>>(out, entb);
    k_phi2<<<1, 128, 0, stream>>>(entb, out + BATCH*32*DD);
}

// Round 4
// 230.589 us; speedup vs baseline: 1.5958x; 1.5958x over previous
//
#include <hip/hip_runtime.h>
#include <hip/hip_bf16.h>
#include <math.h>

// ---------------- sizes ----------------
#define BATCH 128
#define SEQ   2048
#define FIN   128
#define DD    16
#define NLAYERS 6

// ws layout (floats)
#define BUFA_F  (BATCH*SEQ*DD)            // 4,194,304
#define BUFB_F  (BATCH*(SEQ/2)*DD)        // 2,097,152
#define U1_OFF  (BUFA_F + BUFB_F)
#define U2_OFF  (U1_OFF + NLAYERS*4096)
#define WT_OFF  (U2_OFF + NLAYERS*4096)
#define ENT_OFF (WT_OFF + NLAYERS*4096)

// ---------------- prep: u1 = mean_l u, u2 = mean_k u, wt = w transposed ----------------
__global__ __launch_bounds__(256) void k_prep(const float* __restrict__ u,
                                              const float* __restrict__ w,
                                              float* __restrict__ u1,
                                              float* __restrict__ u2,
                                              float* __restrict__ wt) {
    int l  = blockIdx.x;        // 0..5
    int ij = threadIdx.x;       // 0..255  (= i*16+j)
    const float* ub = u + (size_t)l*65536 + (size_t)ij*256;   // [k][l2]
    float a1[16], a2[16];
#pragma unroll
    for (int k = 0; k < 16; ++k) { a1[k] = 0.0f; a2[k] = 0.0f; }
#pragma unroll
    for (int k = 0; k < 16; ++k) {
#pragma unroll
        for (int z = 0; z < 16; ++z) {
            float v = ub[k*16 + z];
            a1[k] += v;
            a2[z] += v;
        }
    }
    float* u1p = u1 + (size_t)l*4096 + ij*16;
    float* u2p = u2 + (size_t)l*4096 + ij*16;
#pragma unroll
    for (int k = 0; k < 16; ++k) { u1p[k] = a1[k]*(1.0f/16.0f); u2p[k] = a2[k]*(1.0f/16.0f); }

    const float* wb = w + (size_t)l*4096;      // [a][i][j]
    float* wtp = wt + (size_t)l*4096 + ij*16;  // [i][j][a]
#pragma unroll
    for (int a = 0; a < 16; ++a) wtp[a] = wb[a*256 + ij];
}

// ---------------- embedding + normalize: 1 thread = 1 row, W via scalar loads ----------------
__global__ __launch_bounds__(256) void k_embed(const float* __restrict__ seq,
                                               const float* __restrict__ W,
                                               const float* __restrict__ bias,
                                               float* __restrict__ out) {
    int t = threadIdx.x;
    size_t row = (size_t)blockIdx.x*256 + t;
    const float4* rp = (const float4*)seq + row*32;
    float acc[16];
#pragma unroll
    for (int d = 0; d < 16; ++d) acc[d] = bias[d];

#pragma unroll 8
    for (int kk = 0; kk < 32; ++kk) {
        float4 rv = rp[kk];
        const float* wr = W + kk*64;      // rows 4kk..4kk+3, wave-uniform -> s_load
#pragma unroll
        for (int d = 0; d < 16; ++d) acc[d] = fmaf(rv.x, wr[d],      acc[d]);
#pragma unroll
        for (int d = 0; d < 16; ++d) acc[d] = fmaf(rv.y, wr[16 + d], acc[d]);
#pragma unroll
        for (int d = 0; d < 16; ++d) acc[d] = fmaf(rv.z, wr[32 + d], acc[d]);
#pragma unroll
        for (int d = 0; d < 16; ++d) acc[d] = fmaf(rv.w, wr[48 + d], acc[d]);
    }
    float p = 0.0f;
#pragma unroll
    for (int d = 0; d < 16; ++d) p = fmaf(acc[d], acc[d], p);
    float inv = 1.0f / fmaxf(sqrtf(p), 1e-12f);
    float4* op = (float4*)(out + row*16);
    op[0] = make_float4(acc[0]*inv,  acc[1]*inv,  acc[2]*inv,  acc[3]*inv);
    op[1] = make_float4(acc[4]*inv,  acc[5]*inv,  acc[6]*inv,  acc[7]*inv);
    op[2] = make_float4(acc[8]*inv,  acc[9]*inv,  acc[10]*inv, acc[11]*inv);
    op[3] = make_float4(acc[12]*inv, acc[13]*inv, acc[14]*inv, acc[15]*inv);
}

// ---------------- one MERA layer: 4 lanes/pair, LDS coeff broadcast, WT reuses U1 space ----
// cbuf[0..4096)   : U1 during phase 1, WT during phase 2
// cbuf[4096..8192): U2
// sp[64][36], o1l[64][20].  Total LDS = 47104 B -> 3 blocks/CU.
__global__ __launch_bounds__(256) void k_layer(const float* __restrict__ in,
                                               float* __restrict__ outp,
                                               const float* __restrict__ u1g,
                                               const float* __restrict__ u2g,
                                               const float* __restrict__ wtg) {
    __shared__ float cbuf[8192];
    __shared__ float sp[64*36];
    __shared__ float o1l[64*20];
    int t = threadIdx.x;

    // WT -> registers early (latency hidden under staging + phase 1)
    const float4* wtf = (const float4*)wtg;
    float4 wreg0 = wtf[0*256 + t];
    float4 wreg1 = wtf[1*256 + t];
    float4 wreg2 = wtf[2*256 + t];
    float4 wreg3 = wtf[3*256 + t];

    // stage U1,U2 (lane-consecutive float4 -> conflict-free)
    {
        const float4* u1f = (const float4*)u1g;
        const float4* u2f = (const float4*)u2g;
        float4* c4 = (float4*)cbuf;
#pragma unroll
        for (int it = 0; it < 4; ++it) {
            c4[it*256 + t]        = u1f[it*256 + t];
            c4[1024 + it*256 + t] = u2f[it*256 + t];
        }
    }
    // stage 64 pairs (512 float4) of site data
    {
        const float4* ing = (const float4*)in + (size_t)blockIdx.x*512;
        float4 v0 = ing[t];
        float4 v1 = ing[t + 256];
        int p0 = t >> 3,         f0 = t & 7;
        int p1 = (t + 256) >> 3, f1 = (t + 256) & 7;
        *(float4*)&sp[p0*36 + f0*4] = v0;
        *(float4*)&sp[p1*36 + f1*4] = v1;
    }
    __syncthreads();

    int pl = t >> 2;        // pair within block 0..63
    int kg = t & 3;         // output k-group (4 outputs per lane)
    int wl = t & 63;        // lane in wave
    int wb = wl & ~3;       // pair base lane in wave

    // s1 (second site) into registers
    float s1[16];
#pragma unroll
    for (int g = 0; g < 4; ++g) {
        float4 v = *(const float4*)&sp[pl*36 + 16 + g*4];
        s1[g*4+0] = v.x; s1[g*4+1] = v.y; s1[g*4+2] = v.z; s1[g*4+3] = v.w;
    }

    const float4* U1f4 = (const float4*)cbuf;          // [ (i*16+j)*4 + kg ]
    const float4* U2f4 = (const float4*)(cbuf + 4096);

    float o1a[4] = {0,0,0,0}, o2a[4] = {0,0,0,0};
    for (int i = 0; i < 16; ++i) {
        float s0i = sp[pl*36 + i];
#pragma unroll
        for (int j = 0; j < 16; ++j) {
            float pij = s0i * s1[j];
            float4 c1 = U1f4[(i*16 + j)*4 + kg];
            float4 c2 = U2f4[(i*16 + j)*4 + kg];
            o1a[0] = fmaf(pij, c1.x, o1a[0]);
            o1a[1] = fmaf(pij, c1.y, o1a[1]);
            o1a[2] = fmaf(pij, c1.z, o1a[2]);
            o1a[3] = fmaf(pij, c1.w, o1a[3]);
            o2a[0] = fmaf(pij, c2.x, o2a[0]);
            o2a[1] = fmaf(pij, c2.y, o2a[1]);
            o2a[2] = fmaf(pij, c2.z, o2a[2]);
            o2a[3] = fmaf(pij, c2.w, o2a[3]);
        }
    }

    // o1 -> LDS (runtime-i access in phase 2); o2 -> full vector via shuffles
    *(float4*)&o1l[pl*20 + kg*4] = make_float4(o1a[0], o1a[1], o1a[2], o1a[3]);
    float o2f[16];
#pragma unroll
    for (int j = 0; j < 16; ++j)
        o2f[j] = __shfl(o2a[j & 3], wb + (j >> 2), 64);

    // all waves done reading U1 -> overwrite with WT
    __syncthreads();
    {
        float4* c4 = (float4*)cbuf;
        c4[0*256 + t] = wreg0;
        c4[1*256 + t] = wreg1;
        c4[2*256 + t] = wreg2;
        c4[3*256 + t] = wreg3;
    }
    __syncthreads();

    const float4* WTf4 = (const float4*)cbuf;
    float acc[4] = {0,0,0,0};
    for (int i = 0; i < 16; ++i) {
        float o1i = o1l[pl*20 + i];
#pragma unroll
        for (int j = 0; j < 16; ++j) {
            float q = o1i * o2f[j];
            float4 cw = WTf4[(i*16 + j)*4 + kg];
            acc[0] = fmaf(q, cw.x, acc[0]);
            acc[1] = fmaf(q, cw.y, acc[1]);
            acc[2] = fmaf(q, cw.z, acc[2]);
            acc[3] = fmaf(q, cw.w, acc[3]);
        }
    }

    size_t gp = (size_t)blockIdx.x*64 + pl;
    *(float4*)(outp + gp*16 + kg*4) = make_float4(acc[0], acc[1], acc[2], acc[3]);
}

// ---------------- phi_q part 1: per-matrix Jacobi, 384 independent blocks ----------------
__device__ __forceinline__ void rot_cs(float al, float be, float ga, float& c, float& s) {
    float ze = (be - al) / (2.0f * ga);
    float tt = copysignf(1.0f, ze) / (fabsf(ze) + sqrtf(1.0f + ze*ze));
    c = 1.0f / sqrtf(1.0f + tt*tt);
    s = c * tt;
}

__global__ __launch_bounds__(64) void k_phi(const float* __restrict__ sites,
                                            float* __restrict__ ent) {
    __shared__ float S[512];
    __shared__ float C[256];
    __shared__ float sv[16];
    int bid = blockIdx.x;
    int role = bid >> 7;          // 0: 16x16 interface, 1: left 8x8, 2: right 8x8
    int b = bid & 127;
    int t = threadIdx.x;
    const float* sp = sites + (size_t)b*512;

    if (role == 0) {
        for (int x = t; x < 512; x += 64) S[x] = sp[x];
        __syncthreads();
        for (int e = t; e < 256; e += 64) {
            int i = e & 15, j = e >> 4;
            float a = 0.0f;
            for (int k = 0; k < 16; ++k) a = fmaf(S[i*16+k], S[(16+j)*16+k], a);
            C[j*16 + i] = a;
        }
        __syncthreads();
        // 16x16 one-sided Jacobi: 8 pairs x 8 lanes (2 rows/lane)
        for (int sw = 0; sw < 12; ++sw) {
            for (int r = 0; r < 15; ++r) {
                int pr = t >> 3, sub = t & 7;
                int p, q;
                if (pr == 0) { p = 15; q = r; }
                else { p = (r + pr) % 15; q = (r + 15 - pr) % 15; }
                float u0 = C[p*16 + 2*sub],   u1v = C[p*16 + 2*sub + 1];
                float v0 = C[q*16 + 2*sub],   v1v = C[q*16 + 2*sub + 1];
                float al = u0*u0 + u1v*u1v;
                float be = v0*v0 + v1v*v1v;
                float ga = u0*v0 + u1v*v1v;
                al += __shfl_xor(al,1); al += __shfl_xor(al,2); al += __shfl_xor(al,4);
                be += __shfl_xor(be,1); be += __shfl_xor(be,2); be += __shfl_xor(be,4);
                ga += __shfl_xor(ga,1); ga += __shfl_xor(ga,2); ga += __shfl_xor(ga,4);
                if (ga != 0.0f) {
                    float c, s; rot_cs(al, be, ga, c, s);
                    C[p*16 + 2*sub]     = fmaf(c, u0, -s*v0);
                    C[p*16 + 2*sub + 1] = fmaf(c, u1v, -s*v1v);
                    C[q*16 + 2*sub]     = fmaf(s, u0,  c*v0);
                    C[q*16 + 2*sub + 1] = fmaf(s, u1v, c*v1v);
                }
                __syncthreads();
            }
        }
        if (t < 16) {
            float s2 = 0.0f;
            for (int rr = 0; rr < 16; ++rr) { float v = C[t*16+rr]; s2 = fmaf(v, v, s2); }
            sv[t] = sqrtf(s2);
        }
        __syncthreads();
        if (t == 0) {
            float sum = 0.0f;
            for (int i2 = 0; i2 < 16; ++i2) sum += sv[i2];
            float den = sum + 1e-8f;
            float e2 = 0.0f;
            for (int i2 = 0; i2 < 16; ++i2) {
                float sn = sv[i2] / den;
                e2 -= sn * logf(sn + 1e-8f);
            }
            ent[b] = e2;
        }
    } else {
        int ro = (role == 1) ? 0 : 256;     // rows 0..15 or 16..31
        for (int x = t; x < 256; x += 64) S[x] = sp[ro + x];
        __syncthreads();
        if (t < 64) {
            int i = t & 7, j = t >> 3;
            float a = 0.0f;
            for (int k = 0; k < 16; ++k) a = fmaf(S[i*16+k], S[(8+j)*16+k], a);
            C[j*8 + i] = a;
        }
        __syncthreads();
        // 8x8: 4 pairs x 8 lanes on lanes 0..31
        for (int sw = 0; sw < 12; ++sw) {
            for (int r = 0; r < 7; ++r) {
                if (t < 32) {
                    int pr = t >> 3, sub = t & 7;
                    int p, q;
                    if (pr == 0) { p = 7; q = r; }
                    else { p = (r + pr) % 7; q = (r + 7 - pr) % 7; }
                    float uu = C[p*8 + sub], vv = C[q*8 + sub];
                    float al = uu*uu, be = vv*vv, ga = uu*vv;
                    al += __shfl_xor(al,1); al += __shfl_xor(al,2); al += __shfl_xor(al,4);
                    be += __shfl_xor(be,1); be += __shfl_xor(be,2); be += __shfl_xor(be,4);
                    ga += __shfl_xor(ga,1); ga += __shfl_xor(ga,2); ga += __shfl_xor(ga,4);
                    if (ga != 0.0f) {
                        float c, s; rot_cs(al, be, ga, c, s);
                        C[p*8 + sub] = fmaf(c, uu, -s*vv);
                        C[q*8 + sub] = fmaf(s, uu,  c*vv);
                    }
                }
                __syncthreads();
            }
        }
        if (t < 8) {
            float s2 = 0.0f;
            for (int rr = 0; rr < 8; ++rr) { float v = C[t*8+rr]; s2 = fmaf(v, v, s2); }
            sv[t] = sqrtf(s2);
        }
        __syncthreads();
        if (t == 0) {
            float sum = 0.0f;
            for (int i2 = 0; i2 < 8; ++i2) sum += sv[i2];
            float den = sum + 1e-8f;
            float e2 = 0.0f;
            for (int i2 = 0; i2 < 8; ++i2) {
                float sn = sv[i2] / den;
                e2 -= sn * logf(sn + 1e-8f);
            }
            ent[role*128 + b] = e2;
        }
    }
}

// ---------------- phi_q part 2: combine entropies ----------------
__global__ __launch_bounds__(128) void k_phi2(const float* __restrict__ ent,
                                              float* __restrict__ phi) {
    int b = threadIdx.x;
    phi[b] = fmaxf(ent[b] - (ent[128 + b] + ent[256 + b]), 0.0f);
}

// ---------------- launcher ----------------
extern "C" void kernel_launch(void* const* d_in, const int* in_sizes, int n_in,
                              void* d_out, int out_size, void* d_ws, size_t ws_size,
                              hipStream_t stream) {
    const float* seq  = (const float*)d_in[0];
    const float* W    = (const float*)d_in[1];
    const float* bias = (const float*)d_in[2];
    const float* u    = (const float*)d_in[3];
    const float* w    = (const float*)d_in[4];
    float* out = (float*)d_out;
    float* ws  = (float*)d_ws;

    float* bufA = ws;
    float* bufB = ws + BUFA_F;
    float* u1   = ws + U1_OFF;
    float* u2   = ws + U2_OFF;
    float* wt   = ws + WT_OFF;
    float* entb = ws + ENT_OFF;

    k_prep <<<NLAYERS, 256, 0, stream>>>(u, w, u1, u2, wt);
    k_embed<<<(BATCH*SEQ)/256, 256, 0, stream>>>(seq, W, bias, bufA);

    const float* lin[6]  = { bufA, bufB, bufA, bufB, bufA, bufB };
    float*       lout[6] = { bufB, bufA, bufB, bufA, bufB, out  };
    int npairs = BATCH * (SEQ/2);
    for (int l = 0; l < NLAYERS; ++l) {
        k_layer<<<npairs/64, 256, 0, stream>>>(lin[l], lout[l],
                                               u1 + l*4096, u2 + l*4096, wt + l*4096);
        npairs >>= 1;
    }
    k_phi <<<3*BATCH, 64, 0, stream>>>(out, entb);
    k_phi2<<<1, 128, 0, stream>>>(entb, out + BATCH*32*DD);
}